// Round 6
// baseline (279.709 us; speedup 1.0000x reference)
//
#include <hip/hip_runtime.h>
#include <math.h>

// ---------------------------------------------------------------------------
// TransformerBlock on MI355X (gfx950).  B=4, N=2048, C=512, H=8, D=64.
// All matmuls bf16 MFMA 16x16x32, fp32 accumulate. Residuals fp32.
// R6: occupancy push. Attention q-tile 64 (grid 2048, 24KB LDS, 6 blocks/CU);
//     GEMM TM=64 tiles (grids 1024-2048, 4+ blocks/CU).
// ---------------------------------------------------------------------------

using bf16x8 = __attribute__((ext_vector_type(8))) short;
using f32x4  = __attribute__((ext_vector_type(4))) float;

typedef unsigned short u16;
typedef unsigned int   u32;

__device__ __forceinline__ u16 f2bf(float f) {
    u32 u; __builtin_memcpy(&u, &f, 4);
    u32 r = u + 0x7FFFu + ((u >> 16) & 1u);   // RNE
    return (u16)(r >> 16);
}
__device__ __forceinline__ u32 fbits(float f) {
    u32 u; __builtin_memcpy(&u, &f, 4); return u;
}
__device__ __forceinline__ float f_from_bits(u32 u) {
    float f; __builtin_memcpy(&f, &u, 4); return f;
}
// pack two f32 -> two bf16 (truncation) in ONE v_perm_b32
__device__ __forceinline__ u32 pack_trunc(float lo, float hi) {
    return __builtin_amdgcn_perm(fbits(hi), fbits(lo), 0x07060302u);
}
// async global->LDS, 16B per lane; LDS dest = wave-uniform base + lane*16
__device__ __forceinline__ void gload16(const void* g, void* l) {
    __builtin_amdgcn_global_load_lds(
        (const __attribute__((address_space(1))) unsigned int*)g,
        (__attribute__((address_space(3))) unsigned int*)l, 16, 0, 0);
}

// ---------------------------------------------------------------------------
// Fused preprocessing: blocks 0..3071 = weight cast+transpose (4 weights),
// blocks 3072..5119 = LayerNorm1 (fp32 x -> bf16 h).
// ---------------------------------------------------------------------------
__global__ __launch_bounds__(256) void k_pre(
        const float* __restrict__ w0, u16* __restrict__ d0,   // 512x1536
        const float* __restrict__ w1, u16* __restrict__ d1,   // 512x512
        const float* __restrict__ w2, u16* __restrict__ d2,   // 512x2048
        const float* __restrict__ w3, u16* __restrict__ d3,   // 2048x512
        const float* __restrict__ x, const float* __restrict__ g,
        const float* __restrict__ bta, u16* __restrict__ hout) {
    __shared__ float tile[32][33];
    const int bid = blockIdx.x;
    if (bid < 3072) {
        const float* w; u16* dst; int K, N, tb;
        if (bid < 768)       { w = w0; dst = d0; K = 512;  N = 1536; tb = bid; }
        else if (bid < 1024) { w = w1; dst = d1; K = 512;  N = 512;  tb = bid - 768; }
        else if (bid < 2048) { w = w2; dst = d2; K = 512;  N = 2048; tb = bid - 1024; }
        else                 { w = w3; dst = d3; K = 2048; N = 512;  tb = bid - 2048; }
        const int nb = N >> 5;
        const int k0 = (tb / nb) << 5;
        const int n0 = (tb % nb) << 5;
        const int c = threadIdx.x & 31, r = threadIdx.x >> 5;
#pragma unroll
        for (int i = 0; i < 4; i++)
            tile[r + i * 8][c] = w[(size_t)(k0 + r + i * 8) * N + n0 + c];
        __syncthreads();
#pragma unroll
        for (int i = 0; i < 4; i++)
            dst[(size_t)(n0 + r + i * 8) * K + k0 + c] = f2bf(tile[c][r + i * 8]);
    } else {
        const int row  = ((bid - 3072) << 2) + (threadIdx.x >> 6);
        const int lane = threadIdx.x & 63;
        const float* xr = x + (size_t)row * 512 + lane * 8;
        float4 a = *(const float4*)xr;
        float4 c = *(const float4*)(xr + 4);
        float s = a.x + a.y + a.z + a.w + c.x + c.y + c.z + c.w;
        float q = a.x*a.x + a.y*a.y + a.z*a.z + a.w*a.w
                + c.x*c.x + c.y*c.y + c.z*c.z + c.w*c.w;
#pragma unroll
        for (int off = 32; off; off >>= 1) {
            s += __shfl_xor(s, off, 64);
            q += __shfl_xor(q, off, 64);
        }
        const float mean = s * (1.0f / 512.0f);
        const float var  = q * (1.0f / 512.0f) - mean * mean;
        const float rstd = rsqrtf(var + 1e-5f);
        float vv[8] = {a.x, a.y, a.z, a.w, c.x, c.y, c.z, c.w};
#pragma unroll
        for (int j = 0; j < 8; j++) {
            const int col = lane * 8 + j;
            hout[(size_t)row * 512 + col] = f2bf((vv[j] - mean) * rstd * g[col] + bta[col]);
        }
    }
}

// ---------------------------------------------------------------------------
// LayerNorm fp32 -> bf16 (standalone, for LN2).
// ---------------------------------------------------------------------------
__global__ __launch_bounds__(256) void k_ln(const float* __restrict__ x,
                                            const float* __restrict__ g,
                                            const float* __restrict__ bta,
                                            u16* __restrict__ out) {
    const int row  = (blockIdx.x << 2) + (threadIdx.x >> 6);
    const int lane = threadIdx.x & 63;
    const float* xr = x + (size_t)row * 512 + lane * 8;
    float4 a = *(const float4*)xr;
    float4 c = *(const float4*)(xr + 4);
    float s = a.x + a.y + a.z + a.w + c.x + c.y + c.z + c.w;
    float q = a.x*a.x + a.y*a.y + a.z*a.z + a.w*a.w
            + c.x*c.x + c.y*c.y + c.z*c.z + c.w*c.w;
#pragma unroll
    for (int off = 32; off; off >>= 1) {
        s += __shfl_xor(s, off, 64);
        q += __shfl_xor(q, off, 64);
    }
    const float mean = s * (1.0f / 512.0f);
    const float var  = q * (1.0f / 512.0f) - mean * mean;
    const float rstd = rsqrtf(var + 1e-5f);
    float vv[8] = {a.x, a.y, a.z, a.w, c.x, c.y, c.z, c.w};
#pragma unroll
    for (int j = 0; j < 8; j++) {
        const int col = lane * 8 + j;
        out[(size_t)row * 512 + col] = f2bf((vv[j] - mean) * rstd * g[col] + bta[col]);
    }
}

// ---------------------------------------------------------------------------
// GEMM: C[M,N] = A[M,K](bf16) @ Bt[N,K]^T + bias. m97 staging, BK=64,
// TMxTN tile (TM=64 for occupancy: weights-B refetch is L2-resident).
// EP=1: +tanh-GELU -> bf16.  EP=2: +fp32 residual -> fp32.
// EP=3: QKV — Q cols (<512) pre-scaled by 0.125*log2e, V cols -> vt transposed.
// 8-chunk XOR swizzle (chunk ^= row&7): b128 reads 2-way (free).
// ---------------------------------------------------------------------------
template <int EP, int TM, int TN>
__global__ __launch_bounds__(256, 4) void k_gemm(const u16* __restrict__ A,
                                                 const u16* __restrict__ Bt,
                                                 const float* __restrict__ bias,
                                                 const float* __restrict__ res,
                                                 float* __restrict__ outF,
                                                 u16* __restrict__ outB,
                                                 u16* __restrict__ out2,
                                                 int M, int N, int K) {
    constexpr int MT = TM / 32;            // 16-row tiles per wave (waves 2x2)
    constexpr int NT = TN / 32;
    __shared__ u16 As[TM * 64];
    __shared__ u16 Bs[TN * 64];
    const int nb = N / TN;
    const int m0 = (blockIdx.x / nb) * TM;
    const int n0 = (blockIdx.x % nb) * TN;
    const int t = threadIdx.x, lane = t & 63, w = t >> 6;
    const int wr = (w >> 1) * (TM / 2);
    const int wc = (w & 1) * (TN / 2);
    const int quad = lane >> 4, l15 = lane & 15;
    const int x7 = l15 & 7;

    f32x4 acc[MT][NT];
#pragma unroll
    for (int i = 0; i < MT; i++)
#pragma unroll
        for (int j = 0; j < NT; j++) acc[i][j] = (f32x4){0.f, 0.f, 0.f, 0.f};

    const size_t Kb = (size_t)K * 2;
    const char* ga = (const char*)A + (size_t)m0 * Kb;
    const char* gb = (const char*)Bt + (size_t)n0 * Kb;
    const int o0 = t * 16;

    for (int k0 = 0; k0 < K; k0 += 64) {
        const int kb = k0 * 2;
#pragma unroll
        for (int i = 0; i < TM / 32; i++) {        // A: TM rows x 128B
            const int o4 = i * 4096 + o0;
            const int row = o4 >> 7;
            const int lc = ((o4 >> 4) & 7) ^ (row & 7);
            gload16(ga + (size_t)row * Kb + kb + lc * 16, (char*)As + o4);
        }
#pragma unroll
        for (int i = 0; i < TN / 32; i++) {        // B: TN rows x 128B
            const int o4 = i * 4096 + o0;
            const int row = o4 >> 7;
            const int lc = ((o4 >> 4) & 7) ^ (row & 7);
            gload16(gb + (size_t)row * Kb + kb + lc * 16, (char*)Bs + o4);
        }
        __syncthreads();
#pragma unroll
        for (int ks = 0; ks < 2; ks++) {
            const int cidx = ((ks * 4 + quad) ^ x7) * 8;
            bf16x8 af[MT], bfr[NT];
#pragma unroll
            for (int i = 0; i < MT; i++)
                af[i] = *(const bf16x8*)(As + (wr + i * 16 + l15) * 64 + cidx);
#pragma unroll
            for (int j = 0; j < NT; j++)
                bfr[j] = *(const bf16x8*)(Bs + (wc + j * 16 + l15) * 64 + cidx);
#pragma unroll
            for (int mt = 0; mt < MT; mt++)
#pragma unroll
                for (int nt = 0; nt < NT; nt++)
                    acc[mt][nt] = __builtin_amdgcn_mfma_f32_16x16x32_bf16(
                        af[mt], bfr[nt], acc[mt][nt], 0, 0, 0);
        }
        __syncthreads();
    }

    const bool vpart = (EP == 3) && (n0 >= 1024);          // block-uniform
    const bool qpart = (EP == 3) && (n0 < 512);            // block-uniform
#pragma unroll
    for (int mt = 0; mt < MT; mt++)
#pragma unroll
        for (int nt = 0; nt < NT; nt++) {
            const int col = n0 + wc + nt * 16 + l15;
            const float bi = bias[col];
            const int row0 = m0 + wr + mt * 16 + quad * 4;
            if (vpart) {
                const int b = row0 >> 11, key = row0 & 2047;
                const int hd = col - 1024;          // h*64 + d
                u32 p0 = (u32)f2bf(acc[mt][nt][0] + bi) |
                         ((u32)f2bf(acc[mt][nt][1] + bi) << 16);
                u32 p1 = (u32)f2bf(acc[mt][nt][2] + bi) |
                         ((u32)f2bf(acc[mt][nt][3] + bi) << 16);
                *(uint2*)(out2 + (size_t)(b * 512 + hd) * 2048 + key) = make_uint2(p0, p1);
            } else {
#pragma unroll
                for (int r = 0; r < 4; r++) {
                    const int row = row0 + r;
                    float v = acc[mt][nt][r] + bi;
                    const size_t oi = (size_t)row * N + col;
                    if (EP == 1) {
                        float y = v * (0.79788456f + 0.035677408f * v * v);
                        y = fminf(y, 40.0f);
                        float tE = exp2f(y * 2.88539008f);
                        v = v * tE * __builtin_amdgcn_rcpf(tE + 1.0f);
                    }
                    if (qpart) v *= 0.18033688f;    // 0.125*log2(e) for attn exp2
                    if (EP == 2) outF[oi] = v + res[oi];
                    else         outB[oi] = f2bf(v);
                }
            }
        }
}

// ---------------------------------------------------------------------------
// Flash attention, transposed + max-free, key-split 2x, q-tile 64, 24KB LDS.
// Grid 2048 = (kh2, b4, h8, qt32); 6 blocks/CU (LDS 160/24). Wave owns 16 q.
// S^T = K Q^T; P^T rows -> wave-private LDS; O^T = V^T P^T. No running max;
// per-lane denominator reduced once at the end. Qs aliases Ks/Vs (prologue).
// ---------------------------------------------------------------------------
__global__ __launch_bounds__(256, 6) void k_attn(const u16* __restrict__ qkv,
                                                 const u16* __restrict__ vt,
                                                 u16* __restrict__ po0,
                                                 u16* __restrict__ po1,
                                                 float* __restrict__ pden) {
    __shared__ u16 smem[12288];              // 24 KB
    u16* Ks = smem;                          // 64 keys x 64 d  (8 KB)
    u16* Vs = smem + 4096;                   // 64 d x 64 keys  (8 KB)
    u16* Psw = smem + 8192;                  // 4 waves x 16 q x 64 keys (8 KB)
    u16* Qs = smem;                          // alias: 64 q x 64 d, prologue only
    const int bid = blockIdx.x;
    const int qt = bid & 31, h = (bid >> 5) & 7, b = (bid >> 8) & 3, kh = bid >> 10;
    const int q0 = qt << 6;
    const int t = threadIdx.x, lane = t & 63, w = t >> 6;
    const int quad = lane >> 4, l15 = lane & 15;
    const int x7 = l15 & 7;

    const char* gq = (const char*)qkv + (size_t)((b << 11) + q0) * 3072 + h * 128;
    const char* gk = (const char*)qkv + (size_t)((b << 11) + (kh << 10)) * 3072 + 1024 + h * 128;
    const char* gv = (const char*)vt + (size_t)((b << 3) + h) * 64 * 4096 + (kh << 10) * 2;

    // stage Q (64 rows x 128B) into aliased region
#pragma unroll
    for (int i = 0; i < 2; i++) {
        const int o4 = i * 4096 + t * 16;
        const int row = o4 >> 7;
        const int lc = ((o4 >> 4) & 7) ^ (row & 7);
        gload16(gq + (size_t)row * 3072 + lc * 16, (char*)Qs + o4);
    }
    __syncthreads();

    // hoist Q fragments (loop-invariant) into registers; wave w: q rows w*16..
    bf16x8 qf[2];
#pragma unroll
    for (int ks = 0; ks < 2; ks++) {
        const int cidx = ((ks * 4 + quad) ^ x7) * 8;
        qf[ks] = *(const bf16x8*)(Qs + (w * 16 + l15) * 64 + cidx);
    }
    __syncthreads();   // all waves done reading Qs before K/V staging overwrites

    f32x4 accO[4];
    float denp = 0.f;
#pragma unroll
    for (int mt = 0; mt < 4; mt++) accO[mt] = (f32x4){0.f, 0.f, 0.f, 0.f};

    for (int kt = 0; kt < 16; kt++) {
        const int kk = kt << 6;
#pragma unroll
        for (int i = 0; i < 2; i++) {
            const int o4 = i * 4096 + t * 16;
            const int row = o4 >> 7;
            const int lc = ((o4 >> 4) & 7) ^ (row & 7);
            gload16(gk + (size_t)(kk + row) * 3072 + lc * 16, (char*)Ks + o4);
            gload16(gv + (size_t)row * 4096 + kk * 2 + lc * 16, (char*)Vs + o4);
        }
        __syncthreads();

        // S^T = K Q^T : rows = 64 keys (4 mt tiles), cols = 16 q
        f32x4 s[4];
#pragma unroll
        for (int mt = 0; mt < 4; mt++) s[mt] = (f32x4){0.f, 0.f, 0.f, 0.f};
#pragma unroll
        for (int ks = 0; ks < 2; ks++) {
            const int cidx = ((ks * 4 + quad) ^ x7) * 8;
#pragma unroll
            for (int mt = 0; mt < 4; mt++) {
                const bf16x8 kf = *(const bf16x8*)(Ks + (mt * 16 + l15) * 64 + cidx);
                s[mt] = __builtin_amdgcn_mfma_f32_16x16x32_bf16(kf, qf[ks], s[mt], 0, 0, 0);
            }
        }

        // p = exp2(s) (scale pre-folded into Q); P^T rows -> Ps[q][key]
#pragma unroll
        for (int mt = 0; mt < 4; mt++) {
            const float p0 = exp2f(s[mt][0]);
            const float p1 = exp2f(s[mt][1]);
            const float p2 = exp2f(s[mt][2]);
            const float p3 = exp2f(s[mt][3]);
            denp += (p0 + p1) + (p2 + p3);
            const u32 d0 = pack_trunc(p0, p1);
            const u32 d1 = pack_trunc(p2, p3);
            const int pidx = l15 * 64 +
                             (((2 * mt + (quad >> 1)) ^ x7) << 3) + (quad & 1) * 4;
            *(uint2*)(&Psw[w * 1024 + pidx]) = make_uint2(d0, d1);
        }

        // O^T += V^T P^T   (Ps wave-private: no barrier needed)
#pragma unroll
        for (int ks = 0; ks < 2; ks++) {
            const int cidx = ((ks * 4 + quad) ^ x7) * 8;
            const bf16x8 pf = *(const bf16x8*)(Psw + w * 1024 + l15 * 64 + cidx);
#pragma unroll
            for (int mt = 0; mt < 4; mt++) {
                const bf16x8 vf = *(const bf16x8*)(Vs + (mt * 16 + l15) * 64 + cidx);
                accO[mt] = __builtin_amdgcn_mfma_f32_16x16x32_bf16(vf, pf, accO[mt], 0, 0, 0);
            }
        }
        __syncthreads();   // Ks/Vs reuse next iter
    }

    // epilogue: partial den (quad-reduced) + raw partial O (bf16)
    u16* po = kh ? po1 : po0;
    float dn = denp;
    dn += __shfl_xor(dn, 16, 64);
    dn += __shfl_xor(dn, 32, 64);
    const int qg = q0 + w * 16 + l15;
    if (quad == 0)
        pden[(size_t)(((kh << 5) + (b << 3) + h) << 11) + qg] = dn;
#pragma unroll
    for (int mt = 0; mt < 4; mt++) {
        const u32 p0 = (u32)f2bf(accO[mt][0]) | ((u32)f2bf(accO[mt][1]) << 16);
        const u32 p1 = (u32)f2bf(accO[mt][2]) | ((u32)f2bf(accO[mt][3]) << 16);
        *(uint2*)(po + (size_t)((b << 11) + qg) * 512 + h * 64 + mt * 16 + quad * 4) =
            make_uint2(p0, p1);
    }
}

// ---------------------------------------------------------------------------
// Combine: o = (po0 + po1) / (den0 + den1), in-place over po0.
// ---------------------------------------------------------------------------
__global__ __launch_bounds__(256) void k_combine(u16* __restrict__ po0,
                                                 const u16* __restrict__ po1,
                                                 const float* __restrict__ pden) {
    const int idx8 = (blockIdx.x * 256 + threadIdx.x) * 8;
    const int row = idx8 >> 9, col = idx8 & 511;
    const int h = col >> 6, q = row & 2047, b = row >> 11;
    const size_t di = (size_t)(((b << 3) + h) << 11) + q;
    const float den = pden[di] + pden[di + (32 << 11)];
    const float r = __builtin_amdgcn_rcpf(den);
    uint4 a = *(const uint4*)(po0 + idx8);
    uint4 c = *(const uint4*)(po1 + idx8);
    u32 av[4] = {a.x, a.y, a.z, a.w}, cv[4] = {c.x, c.y, c.z, c.w}, ov[4];
#pragma unroll
    for (int i = 0; i < 4; i++) {
        const float lo = (f_from_bits(av[i] << 16) + f_from_bits(cv[i] << 16)) * r;
        const float hi = (f_from_bits(av[i] & 0xFFFF0000u) +
                          f_from_bits(cv[i] & 0xFFFF0000u)) * r;
        ov[i] = (u32)f2bf(lo) | ((u32)f2bf(hi) << 16);
    }
    *(uint4*)(po0 + idx8) = make_uint4(ov[0], ov[1], ov[2], ov[3]);
}

// ---------------------------------------------------------------------------
// Host-side pipeline.
// ---------------------------------------------------------------------------
extern "C" void kernel_launch(void* const* d_in, const int* in_sizes, int n_in,
                              void* d_out, int out_size, void* d_ws, size_t ws_size,
                              hipStream_t stream) {
    const float* x      = (const float*)d_in[0];
    const float* ln1_g  = (const float*)d_in[1];
    const float* ln1_b  = (const float*)d_in[2];
    const float* qkv_w  = (const float*)d_in[3];
    const float* qkv_b  = (const float*)d_in[4];
    const float* proj_w = (const float*)d_in[5];
    const float* proj_b = (const float*)d_in[6];
    const float* ln2_g  = (const float*)d_in[7];
    const float* ln2_b  = (const float*)d_in[8];
    const float* fc1_w  = (const float*)d_in[9];
    const float* fc1_b  = (const float*)d_in[10];
    const float* fc2_w  = (const float*)d_in[11];
    const float* fc2_b  = (const float*)d_in[12];
    float* out = (float*)d_out;
    char* ws = (char*)d_ws;

    u16*   qkv_wT = (u16*)(ws + 0);          // 1536x512  bf16
    u16*   proj_wT= (u16*)(ws + 1572864);    // 512x512
    u16*   fc1_wT = (u16*)(ws + 2097152);    // 2048x512
    u16*   fc2_wT = (u16*)(ws + 4194304);    // 512x2048
    u16*   h      = (u16*)(ws + 6291456);    // 8192x512 bf16 (LN outs)
    float* pden   = (float*)(ws + 6291456);  // 512KB, aliases h (dead in attn window)
    u16*   qkv    = (u16*)(ws + 14680064);   // 8192x1536
    u16*   vt     = (u16*)(ws + 39845888);   // [b*8+h][64 d][2048 key]
    u16*   o      = (u16*)(ws + 48234496);   // 8192x512 (= po0, combined in-place)
    u16*   po1    = (u16*)(ws + 56623104);   // aliases x1 (dead until proj)
    float* x1     = (float*)(ws + 56623104); // 8192x512 fp32
    u16*   f1     = (u16*)(ws + 14680064);   // 8192x2048 (reuse qkv+vt)
    u16*   h2     = h;

    // weights cast+T  +  LN1, one launch
    k_pre<<<5120, 256, 0, stream>>>(qkv_w, qkv_wT, proj_w, proj_wT,
                                    fc1_w, fc1_wT, fc2_w, fc2_wT,
                                    x, ln1_g, ln1_b, h);
    // QKV GEMM; Q cols pre-scaled, V cols -> vt transposed
    k_gemm<3,64,128><<<(8192/64)*(1536/128), 256, 0, stream>>>(
        h, qkv_wT, qkv_b, nullptr, nullptr, qkv, vt, 8192, 1536, 512);
    // attention, key-split 2x, q-tile 64 -> partials
    k_attn<<<2048, 256, 0, stream>>>(qkv, vt, o, po1, pden);
    k_combine<<<2048, 256, 0, stream>>>(o, po1, pden);
    // proj GEMM + residual(x) -> x1 fp32
    k_gemm<2,64,64><<<(8192/64)*(512/64), 256, 0, stream>>>(
        o, proj_wT, proj_b, x, x1, nullptr, nullptr, 8192, 512, 512);
    k_ln<<<2048, 256, 0, stream>>>(x1, ln2_g, ln2_b, h2);
    // FC1 + GELU
    k_gemm<1,64,128><<<(8192/64)*(2048/128), 256, 0, stream>>>(
        h2, fc1_wT, fc1_b, nullptr, nullptr, f1, nullptr, 8192, 2048, 512);
    // FC2 + residual(x1) -> out fp32
    k_gemm<2,64,64><<<(8192/64)*(512/64), 256, 0, stream>>>(
        f1, fc2_wT, fc2_b, x1, out, nullptr, nullptr, 8192, 512, 2048);
}

// Round 7
// 244.475 us; speedup vs baseline: 1.1441x; 1.1441x over previous
//
#include <hip/hip_runtime.h>
#include <math.h>

// ---------------------------------------------------------------------------
// TransformerBlock on MI355X (gfx950).  B=4, N=2048, C=512, H=8, D=64.
// All matmuls bf16 MFMA 16x16x32, fp32 accumulate. Residuals fp32.
// R7: revert R6 (q-tile 64 + TM=64 regressed: work/amortization beats
//     occupancy past ~31%). Add XCD-aware block swizzles: attn maps head ->
//     XCD (K/V+Q working set ~3MB fits 4MB L2); GEMM groups m-tiles per XCD
//     (A fetched once instead of 8x).
// ---------------------------------------------------------------------------

using bf16x8 = __attribute__((ext_vector_type(8))) short;
using f32x4  = __attribute__((ext_vector_type(4))) float;

typedef unsigned short u16;
typedef unsigned int   u32;

__device__ __forceinline__ u16 f2bf(float f) {
    u32 u; __builtin_memcpy(&u, &f, 4);
    u32 r = u + 0x7FFFu + ((u >> 16) & 1u);   // RNE
    return (u16)(r >> 16);
}
__device__ __forceinline__ u32 fbits(float f) {
    u32 u; __builtin_memcpy(&u, &f, 4); return u;
}
__device__ __forceinline__ float f_from_bits(u32 u) {
    float f; __builtin_memcpy(&f, &u, 4); return f;
}
// pack two f32 -> two bf16 (truncation) in ONE v_perm_b32
__device__ __forceinline__ u32 pack_trunc(float lo, float hi) {
    return __builtin_amdgcn_perm(fbits(hi), fbits(lo), 0x07060302u);
}
// async global->LDS, 16B per lane; LDS dest = wave-uniform base + lane*16
__device__ __forceinline__ void gload16(const void* g, void* l) {
    __builtin_amdgcn_global_load_lds(
        (const __attribute__((address_space(1))) unsigned int*)g,
        (__attribute__((address_space(3))) unsigned int*)l, 16, 0, 0);
}

// ---------------------------------------------------------------------------
// Fused preprocessing: blocks 0..3071 = weight cast+transpose (4 weights),
// blocks 3072..5119 = LayerNorm1 (fp32 x -> bf16 h).
// ---------------------------------------------------------------------------
__global__ __launch_bounds__(256) void k_pre(
        const float* __restrict__ w0, u16* __restrict__ d0,   // 512x1536
        const float* __restrict__ w1, u16* __restrict__ d1,   // 512x512
        const float* __restrict__ w2, u16* __restrict__ d2,   // 512x2048
        const float* __restrict__ w3, u16* __restrict__ d3,   // 2048x512
        const float* __restrict__ x, const float* __restrict__ g,
        const float* __restrict__ bta, u16* __restrict__ hout) {
    __shared__ float tile[32][33];
    const int bid = blockIdx.x;
    if (bid < 3072) {
        const float* w; u16* dst; int K, N, tb;
        if (bid < 768)       { w = w0; dst = d0; K = 512;  N = 1536; tb = bid; }
        else if (bid < 1024) { w = w1; dst = d1; K = 512;  N = 512;  tb = bid - 768; }
        else if (bid < 2048) { w = w2; dst = d2; K = 512;  N = 2048; tb = bid - 1024; }
        else                 { w = w3; dst = d3; K = 2048; N = 512;  tb = bid - 2048; }
        const int nb = N >> 5;
        const int k0 = (tb / nb) << 5;
        const int n0 = (tb % nb) << 5;
        const int c = threadIdx.x & 31, r = threadIdx.x >> 5;
#pragma unroll
        for (int i = 0; i < 4; i++)
            tile[r + i * 8][c] = w[(size_t)(k0 + r + i * 8) * N + n0 + c];
        __syncthreads();
#pragma unroll
        for (int i = 0; i < 4; i++)
            dst[(size_t)(n0 + r + i * 8) * K + k0 + c] = f2bf(tile[c][r + i * 8]);
    } else {
        const int row  = ((bid - 3072) << 2) + (threadIdx.x >> 6);
        const int lane = threadIdx.x & 63;
        const float* xr = x + (size_t)row * 512 + lane * 8;
        float4 a = *(const float4*)xr;
        float4 c = *(const float4*)(xr + 4);
        float s = a.x + a.y + a.z + a.w + c.x + c.y + c.z + c.w;
        float q = a.x*a.x + a.y*a.y + a.z*a.z + a.w*a.w
                + c.x*c.x + c.y*c.y + c.z*c.z + c.w*c.w;
#pragma unroll
        for (int off = 32; off; off >>= 1) {
            s += __shfl_xor(s, off, 64);
            q += __shfl_xor(q, off, 64);
        }
        const float mean = s * (1.0f / 512.0f);
        const float var  = q * (1.0f / 512.0f) - mean * mean;
        const float rstd = rsqrtf(var + 1e-5f);
        float vv[8] = {a.x, a.y, a.z, a.w, c.x, c.y, c.z, c.w};
#pragma unroll
        for (int j = 0; j < 8; j++) {
            const int col = lane * 8 + j;
            hout[(size_t)row * 512 + col] = f2bf((vv[j] - mean) * rstd * g[col] + bta[col]);
        }
    }
}

// ---------------------------------------------------------------------------
// LayerNorm fp32 -> bf16 (standalone, for LN2).
// ---------------------------------------------------------------------------
__global__ __launch_bounds__(256) void k_ln(const float* __restrict__ x,
                                            const float* __restrict__ g,
                                            const float* __restrict__ bta,
                                            u16* __restrict__ out) {
    const int row  = (blockIdx.x << 2) + (threadIdx.x >> 6);
    const int lane = threadIdx.x & 63;
    const float* xr = x + (size_t)row * 512 + lane * 8;
    float4 a = *(const float4*)xr;
    float4 c = *(const float4*)(xr + 4);
    float s = a.x + a.y + a.z + a.w + c.x + c.y + c.z + c.w;
    float q = a.x*a.x + a.y*a.y + a.z*a.z + a.w*a.w
            + c.x*c.x + c.y*c.y + c.z*c.z + c.w*c.w;
#pragma unroll
    for (int off = 32; off; off >>= 1) {
        s += __shfl_xor(s, off, 64);
        q += __shfl_xor(q, off, 64);
    }
    const float mean = s * (1.0f / 512.0f);
    const float var  = q * (1.0f / 512.0f) - mean * mean;
    const float rstd = rsqrtf(var + 1e-5f);
    float vv[8] = {a.x, a.y, a.z, a.w, c.x, c.y, c.z, c.w};
#pragma unroll
    for (int j = 0; j < 8; j++) {
        const int col = lane * 8 + j;
        out[(size_t)row * 512 + col] = f2bf((vv[j] - mean) * rstd * g[col] + bta[col]);
    }
}

// ---------------------------------------------------------------------------
// GEMM: C[M,N] = A[M,K](bf16) @ Bt[N,K]^T + bias. m97 staging, BK=64,
// 128xTN tile. XCD-grouped decode: xcd = bid&7 owns m-rows m%8==xcd ->
// A-tiles fetched by exactly one XCD; B (<=2MB) L2-resident per XCD.
// EP=1: +tanh-GELU -> bf16.  EP=2: +fp32 residual -> fp32.
// EP=3: QKV — Q cols (<512) pre-scaled by 0.125*log2e, V cols -> vt transposed.
// 8-chunk XOR swizzle (chunk ^= row&7): b128 reads 2-way (free).
// ---------------------------------------------------------------------------
template <int EP, int TN>
__global__ __launch_bounds__(256, 3) void k_gemm(const u16* __restrict__ A,
                                                 const u16* __restrict__ Bt,
                                                 const float* __restrict__ bias,
                                                 const float* __restrict__ res,
                                                 float* __restrict__ outF,
                                                 u16* __restrict__ outB,
                                                 u16* __restrict__ out2,
                                                 int M, int N, int K) {
    constexpr int NT = TN / 32;
    __shared__ u16 As[128 * 64];
    __shared__ u16 Bs[TN * 64];
    const int nb = N / TN;
    // XCD-grouped block decode (grid = (M/128)*nb, M/128 divisible by 8):
    // x = bid&7 -> XCD; within XCD: n fastest (B cycles, L2-resident),
    // m-group slowest (A-tile hot across nb consecutive slots).
    const int xg = blockIdx.x & 7, sg = blockIdx.x >> 3;
    const int m0 = ((sg / nb) * 8 + xg) << 7;
    const int n0 = (sg % nb) * TN;
    const int t = threadIdx.x, lane = t & 63, w = t >> 6;
    const int wr = (w >> 1) << 6;
    const int wc = (w & 1) * (TN / 2);
    const int quad = lane >> 4, l15 = lane & 15;
    const int x7 = l15 & 7;

    f32x4 acc[4][NT];
#pragma unroll
    for (int i = 0; i < 4; i++)
#pragma unroll
        for (int j = 0; j < NT; j++) acc[i][j] = (f32x4){0.f, 0.f, 0.f, 0.f};

    const size_t Kb = (size_t)K * 2;
    const char* ga = (const char*)A + (size_t)m0 * Kb;
    const char* gb = (const char*)Bt + (size_t)n0 * Kb;
    const int o0 = t * 16;

    for (int k0 = 0; k0 < K; k0 += 64) {
        const int kb = k0 * 2;
#pragma unroll
        for (int i = 0; i < 4; i++) {              // A: 128 rows x 128B
            const int o4 = i * 4096 + o0;
            const int row = o4 >> 7;
            const int lc = ((o4 >> 4) & 7) ^ (row & 7);
            gload16(ga + (size_t)row * Kb + kb + lc * 16, (char*)As + o4);
        }
#pragma unroll
        for (int i = 0; i < TN / 32; i++) {        // B: TN rows x 128B
            const int o4 = i * 4096 + o0;
            const int row = o4 >> 7;
            const int lc = ((o4 >> 4) & 7) ^ (row & 7);
            gload16(gb + (size_t)row * Kb + kb + lc * 16, (char*)Bs + o4);
        }
        __syncthreads();
#pragma unroll
        for (int ks = 0; ks < 2; ks++) {
            const int cidx = ((ks * 4 + quad) ^ x7) * 8;
            bf16x8 af[4], bfr[NT];
#pragma unroll
            for (int i = 0; i < 4; i++)
                af[i] = *(const bf16x8*)(As + (wr + i * 16 + l15) * 64 + cidx);
#pragma unroll
            for (int j = 0; j < NT; j++)
                bfr[j] = *(const bf16x8*)(Bs + (wc + j * 16 + l15) * 64 + cidx);
#pragma unroll
            for (int mt = 0; mt < 4; mt++)
#pragma unroll
                for (int nt = 0; nt < NT; nt++)
                    acc[mt][nt] = __builtin_amdgcn_mfma_f32_16x16x32_bf16(
                        af[mt], bfr[nt], acc[mt][nt], 0, 0, 0);
        }
        __syncthreads();
    }

    const bool vpart = (EP == 3) && (n0 >= 1024);          // block-uniform
    const bool qpart = (EP == 3) && (n0 < 512);            // block-uniform
#pragma unroll
    for (int mt = 0; mt < 4; mt++)
#pragma unroll
        for (int nt = 0; nt < NT; nt++) {
            const int col = n0 + wc + nt * 16 + l15;
            const float bi = bias[col];
            const int row0 = m0 + wr + mt * 16 + quad * 4;
            if (vpart) {
                const int b = row0 >> 11, key = row0 & 2047;
                const int hd = col - 1024;          // h*64 + d
                u32 p0 = (u32)f2bf(acc[mt][nt][0] + bi) |
                         ((u32)f2bf(acc[mt][nt][1] + bi) << 16);
                u32 p1 = (u32)f2bf(acc[mt][nt][2] + bi) |
                         ((u32)f2bf(acc[mt][nt][3] + bi) << 16);
                *(uint2*)(out2 + (size_t)(b * 512 + hd) * 2048 + key) = make_uint2(p0, p1);
            } else {
#pragma unroll
                for (int r = 0; r < 4; r++) {
                    const int row = row0 + r;
                    float v = acc[mt][nt][r] + bi;
                    const size_t oi = (size_t)row * N + col;
                    if (EP == 1) {
                        float y = v * (0.79788456f + 0.035677408f * v * v);
                        y = fminf(y, 40.0f);
                        float tE = exp2f(y * 2.88539008f);
                        v = v * tE * __builtin_amdgcn_rcpf(tE + 1.0f);
                    }
                    if (qpart) v *= 0.18033688f;    // 0.125*log2(e) for attn exp2
                    if (EP == 2) outF[oi] = v + res[oi];
                    else         outB[oi] = f2bf(v);
                }
            }
        }
}

// ---------------------------------------------------------------------------
// Flash attention, transposed + max-free, key-split 2x, 32KB LDS, q-tile 128.
// XCD-aware decode: xcd = bid&7 = head h; slot order qt-fastest, (b,kh)
// slowest -> per-XCD working set (4b x 512KB K/V-half + 1MB Q) ~3MB < L2.
// Qs (16KB) aliases Ks/Vs (dead after the register Q-frag hoist).
// ---------------------------------------------------------------------------
__global__ __launch_bounds__(256, 4) void k_attn(const u16* __restrict__ qkv,
                                                 const u16* __restrict__ vt,
                                                 u16* __restrict__ po0,
                                                 u16* __restrict__ po1,
                                                 float* __restrict__ pden) {
    __shared__ u16 smem[16384];              // 32 KB
    u16* Ks = smem;                          // 64 x 64  (8 KB)
    u16* Vs = smem + 4096;                   // 64 x 64  (8 KB)
    u16* Psw = smem + 8192;                  // 4 waves x 32 x 64 (16 KB)
    u16* Qs = smem;                          // alias: 128 x 64 (16 KB), prologue only
    // decode: h = bid&7 (XCD), s = bid>>3: qt = s&15, kh = (s>>4)&1, b = s>>5
    const int bid = blockIdx.x;
    const int h = bid & 7, sg = bid >> 3;
    const int qt = sg & 15, kh = (sg >> 4) & 1, b = sg >> 5;
    const int q0 = qt << 7;
    const int t = threadIdx.x, lane = t & 63, w = t >> 6;
    const int quad = lane >> 4, l15 = lane & 15;
    const int x7 = l15 & 7;

    const char* gq = (const char*)qkv + (size_t)((b << 11) + q0) * 3072 + h * 128;
    const char* gk = (const char*)qkv + (size_t)((b << 11) + (kh << 10)) * 3072 + 1024 + h * 128;
    const char* gv = (const char*)vt + (size_t)((b << 3) + h) * 64 * 4096 + (kh << 10) * 2;

    // stage Q (128 rows x 128B) into aliased region
#pragma unroll
    for (int i = 0; i < 4; i++) {
        const int o4 = i * 4096 + t * 16;
        const int row = o4 >> 7;
        const int lc = ((o4 >> 4) & 7) ^ (row & 7);
        gload16(gq + (size_t)row * 3072 + lc * 16, (char*)Qs + o4);
    }
    __syncthreads();

    // hoist Q fragments (loop-invariant) into registers
    bf16x8 qf[2][2];
#pragma unroll
    for (int ks = 0; ks < 2; ks++) {
        const int cidx = ((ks * 4 + quad) ^ x7) * 8;
#pragma unroll
        for (int nt = 0; nt < 2; nt++)
            qf[ks][nt] = *(const bf16x8*)(Qs + (w * 32 + nt * 16 + l15) * 64 + cidx);
    }
    __syncthreads();   // all waves done reading Qs before K/V staging overwrites

    f32x4 accO[4][2];
    float denp[2] = {0.f, 0.f};
#pragma unroll
    for (int mt = 0; mt < 4; mt++)
#pragma unroll
        for (int nt = 0; nt < 2; nt++) accO[mt][nt] = (f32x4){0.f, 0.f, 0.f, 0.f};

    for (int kt = 0; kt < 16; kt++) {
        const int kk = kt << 6;
#pragma unroll
        for (int i = 0; i < 2; i++) {
            const int o4 = i * 4096 + t * 16;
            const int row = o4 >> 7;
            const int lc = ((o4 >> 4) & 7) ^ (row & 7);
            gload16(gk + (size_t)(kk + row) * 3072 + lc * 16, (char*)Ks + o4);
            gload16(gv + (size_t)row * 4096 + kk * 2 + lc * 16, (char*)Vs + o4);
        }
        __syncthreads();

        // S^T = K Q^T
        f32x4 s[4][2];
#pragma unroll
        for (int mt = 0; mt < 4; mt++)
#pragma unroll
            for (int nt = 0; nt < 2; nt++) s[mt][nt] = (f32x4){0.f, 0.f, 0.f, 0.f};
#pragma unroll
        for (int ks = 0; ks < 2; ks++) {
            const int cidx = ((ks * 4 + quad) ^ x7) * 8;
            bf16x8 kf[4];
#pragma unroll
            for (int mt = 0; mt < 4; mt++)
                kf[mt] = *(const bf16x8*)(Ks + (mt * 16 + l15) * 64 + cidx);
#pragma unroll
            for (int mt = 0; mt < 4; mt++)
#pragma unroll
                for (int nt = 0; nt < 2; nt++)
                    s[mt][nt] = __builtin_amdgcn_mfma_f32_16x16x32_bf16(
                        kf[mt], qf[ks][nt], s[mt][nt], 0, 0, 0);
        }

        // p = exp2(s) (scale pre-folded into Q); write P^T rows to Ps[q][key]
#pragma unroll
        for (int mt = 0; mt < 4; mt++)
#pragma unroll
            for (int nt = 0; nt < 2; nt++) {
                const float p0 = exp2f(s[mt][nt][0]);
                const float p1 = exp2f(s[mt][nt][1]);
                const float p2 = exp2f(s[mt][nt][2]);
                const float p3 = exp2f(s[mt][nt][3]);
                denp[nt] += (p0 + p1) + (p2 + p3);
                const u32 d0 = pack_trunc(p0, p1);
                const u32 d1 = pack_trunc(p2, p3);
                const int pidx = (nt * 16 + l15) * 64 +
                                 (((2 * mt + (quad >> 1)) ^ x7) << 3) + (quad & 1) * 4;
                *(uint2*)(&Psw[w * 2048 + pidx]) = make_uint2(d0, d1);
            }

        // O^T += V^T P^T   (Ps wave-private: no barrier needed)
#pragma unroll
        for (int ks = 0; ks < 2; ks++) {
            const int cidx = ((ks * 4 + quad) ^ x7) * 8;
            bf16x8 vf[4], pf[2];
#pragma unroll
            for (int mt = 0; mt < 4; mt++)
                vf[mt] = *(const bf16x8*)(Vs + (mt * 16 + l15) * 64 + cidx);
#pragma unroll
            for (int nt = 0; nt < 2; nt++)
                pf[nt] = *(const bf16x8*)(Psw + w * 2048 + (nt * 16 + l15) * 64 + cidx);
#pragma unroll
            for (int mt = 0; mt < 4; mt++)
#pragma unroll
                for (int nt = 0; nt < 2; nt++)
                    accO[mt][nt] = __builtin_amdgcn_mfma_f32_16x16x32_bf16(
                        vf[mt], pf[nt], accO[mt][nt], 0, 0, 0);
        }
        __syncthreads();   // Ks/Vs reuse next iter
    }

    // epilogue: partial den (quad-reduced) + raw partial O (bf16)
    u16* po = kh ? po1 : po0;
#pragma unroll
    for (int nt = 0; nt < 2; nt++) {
        float dn = denp[nt];
        dn += __shfl_xor(dn, 16, 64);
        dn += __shfl_xor(dn, 32, 64);
        if (quad == 0)
            pden[(size_t)(((kh << 5) + (b << 3) + h) << 11) + q0 + w * 32 + nt * 16 + l15] = dn;
#pragma unroll
        for (int mt = 0; mt < 4; mt++) {
            const int qg = q0 + w * 32 + nt * 16 + l15;
            const u32 p0 = (u32)f2bf(accO[mt][nt][0]) | ((u32)f2bf(accO[mt][nt][1]) << 16);
            const u32 p1 = (u32)f2bf(accO[mt][nt][2]) | ((u32)f2bf(accO[mt][nt][3]) << 16);
            *(uint2*)(po + (size_t)((b << 11) + qg) * 512 + h * 64 + mt * 16 + quad * 4) =
                make_uint2(p0, p1);
        }
    }
}

// ---------------------------------------------------------------------------
// Combine: o = (po0 + po1) / (den0 + den1), in-place over po0.
// ---------------------------------------------------------------------------
__global__ __launch_bounds__(256) void k_combine(u16* __restrict__ po0,
                                                 const u16* __restrict__ po1,
                                                 const float* __restrict__ pden) {
    const int idx8 = (blockIdx.x * 256 + threadIdx.x) * 8;
    const int row = idx8 >> 9, col = idx8 & 511;
    const int h = col >> 6, q = row & 2047, b = row >> 11;
    const size_t di = (size_t)(((b << 3) + h) << 11) + q;
    const float den = pden[di] + pden[di + (32 << 11)];
    const float r = __builtin_amdgcn_rcpf(den);
    uint4 a = *(const uint4*)(po0 + idx8);
    uint4 c = *(const uint4*)(po1 + idx8);
    u32 av[4] = {a.x, a.y, a.z, a.w}, cv[4] = {c.x, c.y, c.z, c.w}, ov[4];
#pragma unroll
    for (int i = 0; i < 4; i++) {
        const float lo = (f_from_bits(av[i] << 16) + f_from_bits(cv[i] << 16)) * r;
        const float hi = (f_from_bits(av[i] & 0xFFFF0000u) +
                          f_from_bits(cv[i] & 0xFFFF0000u)) * r;
        ov[i] = (u32)f2bf(lo) | ((u32)f2bf(hi) << 16);
    }
    *(uint4*)(po0 + idx8) = make_uint4(ov[0], ov[1], ov[2], ov[3]);
}

// ---------------------------------------------------------------------------
// Host-side pipeline.
// ---------------------------------------------------------------------------
extern "C" void kernel_launch(void* const* d_in, const int* in_sizes, int n_in,
                              void* d_out, int out_size, void* d_ws, size_t ws_size,
                              hipStream_t stream) {
    const float* x      = (const float*)d_in[0];
    const float* ln1_g  = (const float*)d_in[1];
    const float* ln1_b  = (const float*)d_in[2];
    const float* qkv_w  = (const float*)d_in[3];
    const float* qkv_b  = (const float*)d_in[4];
    const float* proj_w = (const float*)d_in[5];
    const float* proj_b = (const float*)d_in[6];
    const float* ln2_g  = (const float*)d_in[7];
    const float* ln2_b  = (const float*)d_in[8];
    const float* fc1_w  = (const float*)d_in[9];
    const float* fc1_b  = (const float*)d_in[10];
    const float* fc2_w  = (const float*)d_in[11];
    const float* fc2_b  = (const float*)d_in[12];
    float* out = (float*)d_out;
    char* ws = (char*)d_ws;

    u16*   qkv_wT = (u16*)(ws + 0);          // 1536x512  bf16
    u16*   proj_wT= (u16*)(ws + 1572864);    // 512x512
    u16*   fc1_wT = (u16*)(ws + 2097152);    // 2048x512
    u16*   fc2_wT = (u16*)(ws + 4194304);    // 512x2048
    u16*   h      = (u16*)(ws + 6291456);    // 8192x512 bf16 (LN outs)
    float* pden   = (float*)(ws + 6291456);  // 512KB, aliases h (dead in attn window)
    u16*   qkv    = (u16*)(ws + 14680064);   // 8192x1536
    u16*   vt     = (u16*)(ws + 39845888);   // [b*8+h][64 d][2048 key]
    u16*   o      = (u16*)(ws + 48234496);   // 8192x512 (= po0, combined in-place)
    u16*   po1    = (u16*)(ws + 56623104);   // aliases x1 (dead until proj)
    float* x1     = (float*)(ws + 56623104); // 8192x512 fp32
    u16*   f1     = (u16*)(ws + 14680064);   // 8192x2048 (reuse qkv+vt)
    u16*   h2     = h;

    // weights cast+T  +  LN1, one launch
    k_pre<<<5120, 256, 0, stream>>>(qkv_w, qkv_wT, proj_w, proj_wT,
                                    fc1_w, fc1_wT, fc2_w, fc2_wT,
                                    x, ln1_g, ln1_b, h);
    // QKV GEMM; Q cols pre-scaled, V cols -> vt transposed
    k_gemm<3,128><<<(8192/128)*(1536/128), 256, 0, stream>>>(
        h, qkv_wT, qkv_b, nullptr, nullptr, qkv, vt, 8192, 1536, 512);
    // attention, key-split 2x -> partials
    k_attn<<<1024, 256, 0, stream>>>(qkv, vt, o, po1, pden);
    k_combine<<<2048, 256, 0, stream>>>(o, po1, pden);
    // proj GEMM + residual(x) -> x1 fp32
    k_gemm<2,64><<<(8192/128)*(512/64), 256, 0, stream>>>(
        o, proj_wT, proj_b, x, x1, nullptr, nullptr, 8192, 512, 512);
    k_ln<<<2048, 256, 0, stream>>>(x1, ln2_g, ln2_b, h2);
    // FC1 + GELU
    k_gemm<1,128><<<(8192/128)*(2048/128), 256, 0, stream>>>(
        h2, fc1_wT, fc1_b, nullptr, nullptr, f1, nullptr, 8192, 2048, 512);
    // FC2 + residual(x1) -> out fp32
    k_gemm<2,64><<<(8192/128)*(512/64), 256, 0, stream>>>(
        f1, fc2_wT, fc2_b, x1, out, nullptr, nullptr, 8192, 512, 2048);
}